// Round 1
// baseline (89891.125 us; speedup 1.0000x reference)
//
#include <hip/hip_runtime.h>
#include <cstddef>

// ---------------------------------------------------------------------------
// CharRNN BN-LSTM (2 layers, recurrent batch norm) + projection + softmax head
// Round 1: correctness-first fp32 implementation.
//   - activations kept TRANSPOSED  h[u][b] so lane=batch gives coalesced loads
//   - per block: 2 H-columns (8 gate cols); K split over 4 waves + LDS reduce
//   - BN stats (mean/var over B=64) = one wave-level shuffle reduction
//   - one phase kernel launch per timestep: phase t = { L1(t), L0(t+1) }
// ---------------------------------------------------------------------------

namespace {
constexpr int kT  = 128;
constexpr int kB  = 64;
constexpr int kNU = 256;
constexpr int kH  = 1024;
constexpr int kV  = 8000;
constexpr int kHB = kH * kB;   // 65536 floats
constexpr int k4H = 4096;
}

__device__ __forceinline__ float wave_sum64(float v) {
#pragma unroll
  for (int off = 32; off > 0; off >>= 1) v += __shfl_xor(v, off, 64);
  return v;
}

__device__ __forceinline__ float sigm(float x) { return 1.0f / (1.0f + expf(-x)); }

struct RecParams {
  const float* xT;      // [T][NU][B]
  float* h0T;           // [2][H][B] double buffer
  float* h1hist;        // [T+1][H][B]
  float* c0T;           // [H][B]
  float* c1T;           // [H][B]
  const float* Wx0; const float* Wh0; const float* b0;
  const float* gx0; const float* gh0; const float* gc0; const float* bc0;
  const float* Wx1; const float* Wh1; const float* b1;
  const float* gx1; const float* gh1; const float* gc1; const float* bc1;
};

// One BN-LSTM layer update for this block's 2 columns.
// inA: "x side" [KA][64] (gamma gA), inB: recurrent side [1024][64] (gamma gB).
__device__ void bnlstm_layer(const float* __restrict__ inA, int KA,
                             const float* __restrict__ WA,
                             const float* __restrict__ inB,
                             const float* __restrict__ WB,
                             const float* __restrict__ bias,
                             const float* __restrict__ gA,
                             const float* __restrict__ gB,
                             const float* __restrict__ gCc,
                             const float* __restrict__ bCc,
                             float* __restrict__ cT,
                             float* __restrict__ hOut,
                             int bid, int w, int lane,
                             float* partRed, float* gateLDS)
{
  const int colBase = 2 * bid;
  float nA0, nA1, nB0, nB1;

  // ---------------- part A: input-side GEMM + BN ----------------
  {
    float acc[8];
#pragma unroll
    for (int j = 0; j < 8; ++j) acc[j] = 0.0f;
    const int ku = KA >> 2;           // K split across 4 waves
    const int u0 = w * ku;
#pragma unroll 4
    for (int u = u0; u < u0 + ku; ++u) {
      const float xv = inA[u * 64 + lane];
      const float* wr = WA + (size_t)u * k4H + colBase;
#pragma unroll
      for (int g = 0; g < 4; ++g) {
        const float2 wp = *(const float2*)(wr + g * 1024);
        acc[2 * g]     += xv * wp.x;
        acc[2 * g + 1] += xv * wp.y;
      }
    }
#pragma unroll
    for (int j = 0; j < 8; ++j) partRed[(w * 8 + j) * 64 + lane] = acc[j];
  }
  __syncthreads();
  {
    float v0 = 0.f, v1 = 0.f;
#pragma unroll
    for (int q = 0; q < 4; ++q) {
      v0 += partRed[(q * 8 + w)     * 64 + lane];
      v1 += partRed[(q * 8 + w + 4) * 64 + lane];
    }
    const float s0 = wave_sum64(v0), q0 = wave_sum64(v0 * v0);
    const float s1 = wave_sum64(v1), q1 = wave_sum64(v1 * v1);
    const float m0 = s0 * 0.015625f, m1 = s1 * 0.015625f;
    const float var0 = q0 * 0.015625f - m0 * m0;
    const float var1 = q1 * 0.015625f - m1 * m1;
    nA0 = (v0 - m0) * rsqrtf(var0 + 1e-5f);
    nA1 = (v1 - m1) * rsqrtf(var1 + 1e-5f);
  }
  __syncthreads();

  // ---------------- part B: recurrent-side GEMM + BN (K=1024) ----------------
  {
    float acc[8];
#pragma unroll
    for (int j = 0; j < 8; ++j) acc[j] = 0.0f;
    const int u0 = w * 256;
#pragma unroll 4
    for (int u = u0; u < u0 + 256; ++u) {
      const float xv = inB[u * 64 + lane];
      const float* wr = WB + (size_t)u * k4H + colBase;
#pragma unroll
      for (int g = 0; g < 4; ++g) {
        const float2 wp = *(const float2*)(wr + g * 1024);
        acc[2 * g]     += xv * wp.x;
        acc[2 * g + 1] += xv * wp.y;
      }
    }
#pragma unroll
    for (int j = 0; j < 8; ++j) partRed[(w * 8 + j) * 64 + lane] = acc[j];
  }
  __syncthreads();
  {
    float v0 = 0.f, v1 = 0.f;
#pragma unroll
    for (int q = 0; q < 4; ++q) {
      v0 += partRed[(q * 8 + w)     * 64 + lane];
      v1 += partRed[(q * 8 + w + 4) * 64 + lane];
    }
    const float s0 = wave_sum64(v0), q0 = wave_sum64(v0 * v0);
    const float s1 = wave_sum64(v1), q1 = wave_sum64(v1 * v1);
    const float m0 = s0 * 0.015625f, m1 = s1 * 0.015625f;
    const float var0 = q0 * 0.015625f - m0 * m0;
    const float var1 = q1 * 0.015625f - m1 * m1;
    nB0 = (v0 - m0) * rsqrtf(var0 + 1e-5f);
    nB1 = (v1 - m1) * rsqrtf(var1 + 1e-5f);
  }

  // gate pre-activations for j=w and j=w+4  (j = g*2 + p)
  {
    const int j0 = w, j1 = w + 4;
    const int gi0 = (j0 >> 1) * 1024 + colBase + (j0 & 1);
    const int gi1 = (j1 >> 1) * 1024 + colBase + (j1 & 1);
    gateLDS[j0 * 64 + lane] = nA0 * gA[gi0] + nB0 * gB[gi0] + bias[gi0];
    gateLDS[j1 * 64 + lane] = nA1 * gA[gi1] + nB1 * gB[gi1] + bias[gi1];
  }
  __syncthreads();

  // c / h update: waves 0,1 handle p = w
  if (w < 2) {
    const int p = w, col = colBase + p;
    const float gi = gateLDS[(0 + p) * 64 + lane];
    const float gj = gateLDS[(2 + p) * 64 + lane];
    const float gf = gateLDS[(4 + p) * 64 + lane];
    const float go = gateLDS[(6 + p) * 64 + lane];
    const float c_old = cT[col * 64 + lane];
    const float c_new = sigm(gf + 1.0f) * c_old + sigm(gi) * tanhf(gj);
    const float s = wave_sum64(c_new), q = wave_sum64(c_new * c_new);
    const float m = s * 0.015625f;
    const float var = q * 0.015625f - m * m;
    const float cn = gCc[col] * (c_new - m) * rsqrtf(var + 1e-5f) + bCc[col];
    const float hn = sigm(go) * tanhf(cn);
    cT[col * 64 + lane]   = c_new;
    hOut[col * 64 + lane] = hn;
  }
  __syncthreads();
}

// phase t: L1(t) (if t>=1) then L0(t+1) (if t<T). 512 blocks x 256 threads.
__global__ __launch_bounds__(256) void phase_k(RecParams P, int t) {
  __shared__ float partRed[4 * 8 * 64];
  __shared__ float gateLDS[8 * 64];
  const int bid  = blockIdx.x;
  const int w    = __builtin_amdgcn_readfirstlane((int)(threadIdx.x >> 6));
  const int lane = threadIdx.x & 63;

  if (t >= 1) {
    bnlstm_layer(P.h0T + (size_t)(t & 1) * kHB, kH, P.Wx1,
                 P.h1hist + (size_t)(t - 1) * kHB, P.Wh1,
                 P.b1, P.gx1, P.gh1, P.gc1, P.bc1,
                 P.c1T, P.h1hist + (size_t)t * kHB,
                 bid, w, lane, partRed, gateLDS);
  }
  if (t < kT) {
    bnlstm_layer(P.xT + (size_t)t * kNU * kB, kNU, P.Wx0,
                 P.h0T + (size_t)(t & 1) * kHB, P.Wh0,
                 P.b0, P.gx0, P.gh0, P.gc0, P.bc0,
                 P.c0T, P.h0T + (size_t)((t + 1) & 1) * kHB,
                 bid, w, lane, partRed, gateLDS);
  }
}

// embedding gather + transpose: xT[t][u][b] = emb[idx[b][t]][u]
__global__ __launch_bounds__(256) void embed_k(const int* __restrict__ idx,
                                               const float* __restrict__ emb,
                                               float* __restrict__ xT) {
  const int t = blockIdx.x;
  __shared__ int rows[kB];
  const int tid = threadIdx.x;
  if (tid < kB) rows[tid] = idx[tid * kT + t];
  __syncthreads();
  float* dst = xT + (size_t)t * kNU * kB;
  for (int i = tid; i < kNU * kB; i += 256) {
    const int u = i >> 6, b = i & 63;
    dst[i] = emb[(size_t)rows[b] * kNU + u];
  }
}

// Y[r = b*T + t][n] = h1(t+1 slot) . Wp[:,n] + bp[n]
__global__ __launch_bounds__(256) void yproj_k(const float* __restrict__ h1hist,
                                               const float* __restrict__ Wp,
                                               const float* __restrict__ bp,
                                               float* __restrict__ Y) {
  const int t  = blockIdx.x;
  const int nq = blockIdx.y;
  const int w    = __builtin_amdgcn_readfirstlane((int)(threadIdx.x >> 6));
  const int lane = threadIdx.x & 63;
  const int n0 = nq * 64 + w * 16;
  const float* hin = h1hist + (size_t)(t + 1) * kHB;
  float acc[16];
#pragma unroll
  for (int k = 0; k < 16; ++k) acc[k] = 0.0f;
#pragma unroll 4
  for (int u = 0; u < kH; ++u) {
    const float xv = hin[u * 64 + lane];
    const float4* wr = (const float4*)(Wp + (size_t)u * kNU + n0);
#pragma unroll
    for (int q = 0; q < 4; ++q) {
      const float4 wv = wr[q];
      acc[q * 4 + 0] += xv * wv.x;
      acc[q * 4 + 1] += xv * wv.y;
      acc[q * 4 + 2] += xv * wv.z;
      acc[q * 4 + 3] += xv * wv.w;
    }
  }
  float* yr = Y + ((size_t)lane * kT + t) * kNU + n0;
#pragma unroll
  for (int k = 0; k < 16; ++k) yr[k] = acc[k] + bp[n0 + k];
}

// logits[r][v] = Y[r][:] . SW[:,v] + sb[v].  Block: 64 r x 128 v, K = 256.
__global__ __launch_bounds__(256) void gemm2_k(const float* __restrict__ Y,
                                               const float* __restrict__ SW,
                                               const float* __restrict__ sb,
                                               float* __restrict__ out) {
  __shared__ float A[64 * 256];   // 64 KB
  const int r0 = blockIdx.x * 64;
  const int v0 = blockIdx.y * 128;
  const int tid = threadIdx.x;
  {
    const float4* src = (const float4*)(Y + (size_t)r0 * kNU);
    float4* dst = (float4*)A;
    for (int i = tid; i < 64 * 64; i += 256) dst[i] = src[i];
  }
  __syncthreads();
  const int tv = tid & 15, tr = tid >> 4;
  const int v = v0 + tv * 8;
  if (v + 7 >= kV) return;   // whole-thread guard (tile tail); barrier already passed
  float acc[4][8];
#pragma unroll
  for (int i = 0; i < 4; ++i)
#pragma unroll
    for (int k = 0; k < 8; ++k) acc[i][k] = 0.0f;

  for (int n = 0; n < 256; ++n) {
    const float4 b0 = *(const float4*)(SW + (size_t)n * kV + v);
    const float4 b1 = *(const float4*)(SW + (size_t)n * kV + v + 4);
#pragma unroll
    for (int i = 0; i < 4; ++i) {
      const float a = A[(tr * 4 + i) * 256 + n];
      acc[i][0] += a * b0.x; acc[i][1] += a * b0.y;
      acc[i][2] += a * b0.z; acc[i][3] += a * b0.w;
      acc[i][4] += a * b1.x; acc[i][5] += a * b1.y;
      acc[i][6] += a * b1.z; acc[i][7] += a * b1.w;
    }
  }
#pragma unroll
  for (int i = 0; i < 4; ++i) {
    const size_t r = (size_t)(r0 + tr * 4 + i);
    float* o = out + r * kV + v;
#pragma unroll
    for (int k = 0; k < 8; ++k) o[k] = acc[i][k] + sb[v + k];
  }
}

extern "C" void kernel_launch(void* const* d_in, const int* in_sizes, int n_in,
                              void* d_out, int out_size, void* d_ws, size_t ws_size,
                              hipStream_t stream) {
  (void)in_sizes; (void)n_in; (void)out_size; (void)ws_size;
  const int*   idx = (const int*)d_in[0];
  const float* emb = (const float*)d_in[1];
  RecParams P;
  P.Wx0 = (const float*)d_in[2];  P.Wh0 = (const float*)d_in[3];
  P.b0  = (const float*)d_in[4];  P.gx0 = (const float*)d_in[5];
  P.gh0 = (const float*)d_in[6];  P.gc0 = (const float*)d_in[7];
  P.bc0 = (const float*)d_in[8];
  P.Wx1 = (const float*)d_in[9];  P.Wh1 = (const float*)d_in[10];
  P.b1  = (const float*)d_in[11]; P.gx1 = (const float*)d_in[12];
  P.gh1 = (const float*)d_in[13]; P.gc1 = (const float*)d_in[14];
  P.bc1 = (const float*)d_in[15];
  const float* Wp = (const float*)d_in[16];
  const float* bp = (const float*)d_in[17];
  const float* SW = (const float*)d_in[18];
  const float* sb = (const float*)d_in[19];

  float* ws = (float*)d_ws;
  size_t off = 0;
  float* xT     = ws + off; off += (size_t)kT * kNU * kB;     // 2,097,152
  float* h0T    = ws + off; off += 2 * (size_t)kHB;           // 131,072
  float* h1hist = ws + off; off += (size_t)(kT + 1) * kHB;    // 8,454,144
  float* c0T    = ws + off; off += kHB;
  float* c1T    = ws + off; off += kHB;
  float* Y      = ws + off; off += (size_t)kT * kB * kNU;     // 2,097,152

  P.xT = xT; P.h0T = h0T; P.h1hist = h1hist; P.c0T = c0T; P.c1T = c1T;

  // zero-init initial states (ws is poisoned 0xAA before every launch)
  hipMemsetAsync(h0T, 0, (size_t)kHB * sizeof(float), stream);          // slot 0 only
  hipMemsetAsync(h1hist, 0, (size_t)kHB * sizeof(float), stream);       // slot 0 only
  hipMemsetAsync(c0T, 0, (size_t)kHB * sizeof(float), stream);
  hipMemsetAsync(c1T, 0, (size_t)kHB * sizeof(float), stream);

  embed_k<<<kT, 256, 0, stream>>>(idx, emb, xT);

  for (int t = 0; t <= kT; ++t)
    phase_k<<<512, 256, 0, stream>>>(P, t);

  yproj_k<<<dim3(kT, 4), 256, 0, stream>>>(h1hist, Wp, bp, Y);

  gemm2_k<<<dim3(8192 / 64, 63), 256, 0, stream>>>(Y, SW, sb, (float*)d_out);
}